// Round 8
// baseline (648.431 us; speedup 1.0000x reference)
//
#include <hip/hip_runtime.h>

#define NN 100000
#define NE 1600000
#define NG 256
#define NB 391   // ceil(NN/256)

__global__ __launch_bounds__(256) void zero_kernel(float* __restrict__ p, int n) {
    int i = blockIdx.x * 256 + threadIdx.x;
    if (i < n) p[i] = 0.f;
}

// ---------------- CSR build ----------------
__global__ __launch_bounds__(256) void count_kernel(
    const int* __restrict__ col, unsigned* __restrict__ cnt) {
    int e = blockIdx.x * 256 + threadIdx.x;       // grid covers NE exactly
    atomicAdd(&cnt[col[e]], 1u);
}

// batch is sorted: graph g starts where batch steps past g. No atomics.
__global__ __launch_bounds__(256) void gbound_kernel(
    const int* __restrict__ batch, int* __restrict__ gstart) {
    int n = blockIdx.x * 256 + threadIdx.x;
    if (n >= NN) return;
    int b = batch[n];
    int bp = (n == 0) ? -1 : batch[n - 1];
    for (int g = bp + 1; g <= b; ++g) gstart[g] = n;
    if (n == NN - 1) {
        for (int g = b + 1; g <= NG; ++g) gstart[g] = NN;
    }
}

__global__ __launch_bounds__(256) void bsum_kernel(
    const unsigned* __restrict__ cnt, unsigned* __restrict__ bsum) {
    __shared__ unsigned sm[256];
    int i = blockIdx.x * 256 + threadIdx.x;
    sm[threadIdx.x] = (i < NN) ? cnt[i] : 0u;
    __syncthreads();
    for (int s = 128; s > 0; s >>= 1) {
        if (threadIdx.x < s) sm[threadIdx.x] += sm[threadIdx.x + s];
        __syncthreads();
    }
    if (threadIdx.x == 0) bsum[blockIdx.x] = sm[0];
}

__global__ __launch_bounds__(512) void bscan_kernel(
    const unsigned* __restrict__ bsum, unsigned* __restrict__ boff) {
    __shared__ unsigned a[512], b[512];
    int t = threadIdx.x;
    a[t] = (t < NB) ? bsum[t] : 0u;
    __syncthreads();
    unsigned* src = a; unsigned* dst = b;
    for (int off = 1; off < 512; off <<= 1) {
        unsigned v = src[t];
        if (t >= off) v += src[t - off];
        dst[t] = v;
        __syncthreads();
        unsigned* tmp = src; src = dst; dst = tmp;
    }
    if (t < NB) boff[t] = (t == 0) ? 0u : src[t - 1];
}

__global__ __launch_bounds__(256) void start_kernel(
    const unsigned* __restrict__ cnt, const unsigned* __restrict__ boff,
    unsigned* __restrict__ start, unsigned* __restrict__ cursor) {
    __shared__ unsigned a[256], b[256];
    int t = threadIdx.x;
    int i = blockIdx.x * 256 + t;
    unsigned v = (i < NN) ? cnt[i] : 0u;
    a[t] = v;
    __syncthreads();
    unsigned* src = a; unsigned* dst = b;
    for (int off = 1; off < 256; off <<= 1) {
        unsigned x = src[t];
        if (t >= off) x += src[t - off];
        dst[t] = x;
        __syncthreads();
        unsigned* tmp = src; src = dst; dst = tmp;
    }
    unsigned excl = src[t] - v;
    unsigned st = boff[blockIdx.x] + excl;
    if (i < NN) {
        start[i] = st;
        cursor[i] = st;
        if (i == NN - 1) start[NN] = st + v;
    }
}

// random 4B write of edge index into sorted slot (replaces 20B random write)
__global__ __launch_bounds__(256) void pos_kernel(
    const int* __restrict__ col, unsigned* __restrict__ cursor,
    int* __restrict__ eidx) {
    int e = blockIdx.x * 256 + threadIdx.x;       // grid covers NE exactly
    unsigned t = atomicAdd(&cursor[col[e]], 1u);
    eidx[t] = e;
}

// gather form: coalesced eidx read + coalesced rc/eab writes; randomness is
// on the READ side (L2/L3-cached, no partial-line RMW)
__global__ __launch_bounds__(256) void permute_kernel(
    const int* __restrict__ eidx,
    const int* __restrict__ row, const int* __restrict__ col,
    const float* __restrict__ ea,
    int2* __restrict__ rc, float* __restrict__ eab) {
    int t = blockIdx.x * 256 + threadIdx.x;       // grid covers NE exactly
    int e = eidx[t];
    rc[t] = make_int2(row[e], col[e]);
    eab[(size_t)t * 3 + 0] = ea[(size_t)e * 3 + 0];
    eab[(size_t)t * 3 + 1] = ea[(size_t)e * 3 + 1];
    eab[(size_t)t * 3 + 2] = ea[(size_t)e * 3 + 2];
}

// ---------------- weight prep (padded rows) ----------------
//   ewt: 2 x 128 x 24  [W1[0..16][j], b1[j], W2[j][0..2], pad x3]
//   nwt: 2 x 128 x 28  [W1[0..17][j], b1[j], W2[j][0..6], pad x2]
__global__ __launch_bounds__(256) void prep_kernel(
    const float* __restrict__ eW1, const float* __restrict__ eb1, const float* __restrict__ eW2,
    const float* __restrict__ nW1, const float* __restrict__ nb1, const float* __restrict__ nW2,
    float* __restrict__ ewt, float* __restrict__ nwt)
{
    int t = blockIdx.x * 256 + threadIdx.x;
    const int ESZ = 2 * 128 * 24;
    const int NSZ = 2 * 128 * 28;
    if (t < ESZ) {
        int l = t / (128 * 24), rest = t % (128 * 24), j = rest / 24, i = rest % 24;
        float v = 0.f;
        if (i < 17)       v = eW1[l * 17 * 128 + i * 128 + j];
        else if (i == 17) v = eb1[l * 128 + j];
        else if (i < 21)  v = eW2[l * 128 * 3 + j * 3 + (i - 18)];
        ewt[t] = v;
    } else if (t < ESZ + NSZ) {
        int q = t - ESZ;
        int l = q / (128 * 28), rest = q % (128 * 28), j = rest / 28, i = rest % 28;
        float v = 0.f;
        if (i < 18)       v = nW1[l * 18 * 128 + i * 128 + j];
        else if (i == 18) v = nb1[l * 128 + j];
        else if (i < 26)  v = nW2[l * 128 * 7 + j * 7 + (i - 19)];
        nwt[q] = v;
    }
}

// ---------------- edge MLP: 4 edges/thread, scalar weights ----------------
// grid = ceil(NE/1024); only last block partially covered.
__global__ __launch_bounds__(256) void edge_kernel(
    const float* __restrict__ x, float* eab,
    const int2* __restrict__ rc,
    const float* __restrict__ wt, const float* __restrict__ b2)
{
    int base = blockIdx.x * 1024 + threadIdx.x;
    int tt[4];
    bool ok[4];
    float in[4][17];

    #pragma unroll
    for (int k = 0; k < 4; ++k) {
        int t = base + k * 256;
        ok[k] = (t < NE);
        tt[k] = ok[k] ? t : 0;
        int2 p = rc[tt[k]];
        const float* xr = x + (size_t)p.x * 7;
        const float* xc = x + (size_t)p.y * 7;
        #pragma unroll
        for (int i = 0; i < 7; ++i) in[k][i] = xr[i];
        #pragma unroll
        for (int i = 0; i < 7; ++i) in[k][7 + i] = xc[i];
        #pragma unroll
        for (int i = 0; i < 3; ++i) in[k][14 + i] = eab[(size_t)tt[k] * 3 + i];
    }

    // pin gathers into VGPRs: loads cannot be sunk/rematerialized into the loop
    asm volatile("" : "+v"(in[0][0]), "+v"(in[0][1]), "+v"(in[0][2]), "+v"(in[0][3]),
                      "+v"(in[0][4]), "+v"(in[0][5]), "+v"(in[0][6]), "+v"(in[0][7]),
                      "+v"(in[0][8]), "+v"(in[0][9]), "+v"(in[0][10]), "+v"(in[0][11]),
                      "+v"(in[0][12]), "+v"(in[0][13]), "+v"(in[0][14]), "+v"(in[0][15]),
                      "+v"(in[0][16]));
    asm volatile("" : "+v"(in[1][0]), "+v"(in[1][1]), "+v"(in[1][2]), "+v"(in[1][3]),
                      "+v"(in[1][4]), "+v"(in[1][5]), "+v"(in[1][6]), "+v"(in[1][7]),
                      "+v"(in[1][8]), "+v"(in[1][9]), "+v"(in[1][10]), "+v"(in[1][11]),
                      "+v"(in[1][12]), "+v"(in[1][13]), "+v"(in[1][14]), "+v"(in[1][15]),
                      "+v"(in[1][16]));
    asm volatile("" : "+v"(in[2][0]), "+v"(in[2][1]), "+v"(in[2][2]), "+v"(in[2][3]),
                      "+v"(in[2][4]), "+v"(in[2][5]), "+v"(in[2][6]), "+v"(in[2][7]),
                      "+v"(in[2][8]), "+v"(in[2][9]), "+v"(in[2][10]), "+v"(in[2][11]),
                      "+v"(in[2][12]), "+v"(in[2][13]), "+v"(in[2][14]), "+v"(in[2][15]),
                      "+v"(in[2][16]));
    asm volatile("" : "+v"(in[3][0]), "+v"(in[3][1]), "+v"(in[3][2]), "+v"(in[3][3]),
                      "+v"(in[3][4]), "+v"(in[3][5]), "+v"(in[3][6]), "+v"(in[3][7]),
                      "+v"(in[3][8]), "+v"(in[3][9]), "+v"(in[3][10]), "+v"(in[3][11]),
                      "+v"(in[3][12]), "+v"(in[3][13]), "+v"(in[3][14]), "+v"(in[3][15]),
                      "+v"(in[3][16]));

    float acc[4][3];
    #pragma unroll
    for (int k = 0; k < 4; ++k) { acc[k][0] = 0.f; acc[k][1] = 0.f; acc[k][2] = 0.f; }

    #pragma unroll 4
    for (int j = 0; j < 128; ++j) {
        const float* wr = wt + __builtin_amdgcn_readfirstlane(j * 24);
        float w[21];
        #pragma unroll
        for (int i = 0; i < 21; ++i) w[i] = wr[i];
        float h0[4], h1[4];
        #pragma unroll
        for (int k = 0; k < 4; ++k) { h0[k] = w[17]; h1[k] = 0.f; }
        #pragma unroll
        for (int k = 0; k < 4; ++k) {
            h0[k] += in[k][0] * w[0];   h1[k] += in[k][1] * w[1];
            h0[k] += in[k][2] * w[2];   h1[k] += in[k][3] * w[3];
            h0[k] += in[k][4] * w[4];   h1[k] += in[k][5] * w[5];
            h0[k] += in[k][6] * w[6];   h1[k] += in[k][7] * w[7];
            h0[k] += in[k][8] * w[8];   h1[k] += in[k][9] * w[9];
            h0[k] += in[k][10] * w[10]; h1[k] += in[k][11] * w[11];
            h0[k] += in[k][12] * w[12]; h1[k] += in[k][13] * w[13];
            h0[k] += in[k][14] * w[14]; h1[k] += in[k][15] * w[15];
            h0[k] += in[k][16] * w[16];
        }
        #pragma unroll
        for (int k = 0; k < 4; ++k) {
            float h = fmaxf(h0[k] + h1[k], 0.f);
            acc[k][0] += h * w[18];
            acc[k][1] += h * w[19];
            acc[k][2] += h * w[20];
        }
    }

    float bb0 = b2[0], bb1 = b2[1], bb2 = b2[2];
    #pragma unroll
    for (int k = 0; k < 4; ++k) {
        if (ok[k]) {
            eab[(size_t)tt[k] * 3 + 0] = acc[k][0] + bb0;
            eab[(size_t)tt[k] * 3 + 1] = acc[k][1] + bb1;
            eab[(size_t)tt[k] * 3 + 2] = acc[k][2] + bb2;
        }
    }
}

// ---------------- segment reduce: 16 lanes per node ----------------
// writes nred[n][12] = [s0,s1,s2, m0,m1,m2, mean0,mean1,mean2, u0,u1, pad]
__global__ __launch_bounds__(256) void reduce_kernel(
    const float* __restrict__ eab, const unsigned* __restrict__ start,
    const float* __restrict__ u, const int* __restrict__ batch,
    float* __restrict__ nred)
{
    int gid = blockIdx.x * 256 + threadIdx.x;
    int n = gid >> 4, sub = gid & 15;
    if (n >= NN) return;
    unsigned sbeg = start[n], send = start[n + 1];

    float s0 = 0.f, s1 = 0.f, s2 = 0.f;
    float m0 = -__builtin_inff(), m1 = -__builtin_inff(), m2 = -__builtin_inff();
    for (unsigned k = sbeg + sub; k < send; k += 16) {
        float v0 = eab[(size_t)k * 3 + 0];
        float v1 = eab[(size_t)k * 3 + 1];
        float v2 = eab[(size_t)k * 3 + 2];
        s0 += v0; s1 += v1; s2 += v2;
        m0 = fmaxf(m0, v0); m1 = fmaxf(m1, v1); m2 = fmaxf(m2, v2);
    }
    #pragma unroll
    for (int msk = 1; msk < 16; msk <<= 1) {
        s0 += __shfl_xor(s0, msk, 16);
        s1 += __shfl_xor(s1, msk, 16);
        s2 += __shfl_xor(s2, msk, 16);
        m0 = fmaxf(m0, __shfl_xor(m0, msk, 16));
        m1 = fmaxf(m1, __shfl_xor(m1, msk, 16));
        m2 = fmaxf(m2, __shfl_xor(m2, msk, 16));
    }
    if (sub == 0) {
        float deg = (float)(send - sbeg);
        if (send == sbeg) { m0 = 0.f; m1 = 0.f; m2 = 0.f; }
        float inv = 1.f / fmaxf(deg, 1.f);
        int b = batch[n];
        float* o = nred + (size_t)n * 12;
        o[0] = s0; o[1] = s1; o[2] = s2;
        o[3] = m0; o[4] = m1; o[5] = m2;
        o[6] = s0 * inv; o[7] = s1 * inv; o[8] = s2 * inv;
        o[9] = u[b * 2 + 0]; o[10] = u[b * 2 + 1];
    }
}

// ---------------- node MLP: wave-per-node, weight-stationary ----------------
#define NMLP_BLOCKS 1024
#define NMLP_WAVES (NMLP_BLOCKS * 4)
__global__ __launch_bounds__(256, 4) void nodemlp_kernel(
    const float* x_in, const float* __restrict__ nred,
    const float* __restrict__ wt, const float* __restrict__ b2,
    float* x_out)
{
    int lane = threadIdx.x & 63;
    int wid = (blockIdx.x * 256 + threadIdx.x) >> 6;

    const float* ra = wt + lane * 28;
    const float* rb = wt + (lane + 64) * 28;
    float a0 = ra[0], a1 = ra[1], a2 = ra[2], a3 = ra[3], a4 = ra[4], a5 = ra[5],
          a6 = ra[6], a7 = ra[7], a8 = ra[8], a9 = ra[9], a10 = ra[10], a11 = ra[11],
          a12 = ra[12], a13 = ra[13], a14 = ra[14], a15 = ra[15], a16 = ra[16], a17 = ra[17],
          ab = ra[18], p0 = ra[19], p1 = ra[20], p2 = ra[21], p3 = ra[22], p4 = ra[23],
          p5 = ra[24], p6 = ra[25];
    float b0 = rb[0], b1 = rb[1], b2_ = rb[2], b3 = rb[3], b4 = rb[4], b5 = rb[5],
          b6 = rb[6], b7 = rb[7], b8 = rb[8], b9 = rb[9], b10 = rb[10], b11 = rb[11],
          b12 = rb[12], b13 = rb[13], b14 = rb[14], b15 = rb[15], b16 = rb[16], b17 = rb[17],
          bb = rb[18], q0 = rb[19], q1 = rb[20], q2 = rb[21], q3 = rb[22], q4 = rb[23],
          q5 = rb[24], q6 = rb[25];

    asm volatile("" : "+v"(a0), "+v"(a1), "+v"(a2), "+v"(a3), "+v"(a4), "+v"(a5),
                      "+v"(a6), "+v"(a7), "+v"(a8), "+v"(a9), "+v"(a10), "+v"(a11),
                      "+v"(a12), "+v"(a13), "+v"(a14), "+v"(a15), "+v"(a16), "+v"(a17),
                      "+v"(ab), "+v"(p0), "+v"(p1), "+v"(p2), "+v"(p3), "+v"(p4),
                      "+v"(p5), "+v"(p6));
    asm volatile("" : "+v"(b0), "+v"(b1), "+v"(b2_), "+v"(b3), "+v"(b4), "+v"(b5),
                      "+v"(b6), "+v"(b7), "+v"(b8), "+v"(b9), "+v"(b10), "+v"(b11),
                      "+v"(b12), "+v"(b13), "+v"(b14), "+v"(b15), "+v"(b16), "+v"(b17),
                      "+v"(bb), "+v"(q0), "+v"(q1), "+v"(q2), "+v"(q3), "+v"(q4),
                      "+v"(q5), "+v"(q6));

    float B0 = b2[0], B1 = b2[1], B2 = b2[2], B3 = b2[3], B4 = b2[4], B5 = b2[5], B6 = b2[6];

    const int nper = (NN + NMLP_WAVES - 1) / NMLP_WAVES;   // 25
    int n0 = wid * nper;
    int n1 = n0 + nper; if (n1 > NN) n1 = NN;

    #pragma unroll 2
    for (int n = n0; n < n1; ++n) {
        int nu = __builtin_amdgcn_readfirstlane(n);
        const float* xp = x_in + (size_t)nu * 7;
        const float* rp = nred + (size_t)nu * 12;
        float i0 = xp[0], i1 = xp[1], i2 = xp[2], i3 = xp[3], i4 = xp[4], i5 = xp[5], i6 = xp[6];
        float s0 = rp[0], s1 = rp[1], s2 = rp[2];
        float m0 = rp[3], m1 = rp[4], m2 = rp[5];
        float e0 = rp[6], e1 = rp[7], e2 = rp[8];
        float u0 = rp[9], u1 = rp[10];

        float ha = ab, hb = bb;
        ha += i0 * a0;  hb += i0 * b0;
        ha += i1 * a1;  hb += i1 * b1;
        ha += i2 * a2;  hb += i2 * b2_;
        ha += i3 * a3;  hb += i3 * b3;
        ha += i4 * a4;  hb += i4 * b4;
        ha += i5 * a5;  hb += i5 * b5;
        ha += i6 * a6;  hb += i6 * b6;
        ha += s0 * a7;  hb += s0 * b7;
        ha += s1 * a8;  hb += s1 * b8;
        ha += s2 * a9;  hb += s2 * b9;
        ha += m0 * a10; hb += m0 * b10;
        ha += m1 * a11; hb += m1 * b11;
        ha += m2 * a12; hb += m2 * b12;
        ha += e0 * a13; hb += e0 * b13;
        ha += e1 * a14; hb += e1 * b14;
        ha += e2 * a15; hb += e2 * b15;
        ha += u0 * a16; hb += u0 * b16;
        ha += u1 * a17; hb += u1 * b17;
        ha = fmaxf(ha, 0.f); hb = fmaxf(hb, 0.f);

        float c0 = ha * p0 + hb * q0;
        float c1 = ha * p1 + hb * q1;
        float c2 = ha * p2 + hb * q2;
        float c3 = ha * p3 + hb * q3;
        float c4 = ha * p4 + hb * q4;
        float c5 = ha * p5 + hb * q5;
        float c6 = ha * p6 + hb * q6;
        #pragma unroll
        for (int msk = 1; msk < 64; msk <<= 1) {
            c0 += __shfl_xor(c0, msk);
            c1 += __shfl_xor(c1, msk);
            c2 += __shfl_xor(c2, msk);
            c3 += __shfl_xor(c3, msk);
            c4 += __shfl_xor(c4, msk);
            c5 += __shfl_xor(c5, msk);
            c6 += __shfl_xor(c6, msk);
        }
        float o = c0 + B0;
        if (lane == 1) o = c1 + B1;
        if (lane == 2) o = c2 + B2;
        if (lane == 3) o = c3 + B3;
        if (lane == 4) o = c4 + B4;
        if (lane == 5) o = c5 + B5;
        if (lane == 6) o = c6 + B6;
        if (lane < 7) x_out[(size_t)nu * 7 + lane] = o;
    }
}

// ---------------- fused graph pool + output head (block per graph) ----------
__global__ __launch_bounds__(256) void pool_head_kernel(
    const float* __restrict__ x, const int* __restrict__ gstart,
    const float* __restrict__ u,
    const float* __restrict__ oW1, const float* __restrict__ ob1,
    const float* __restrict__ oW2, const float* __restrict__ ob2,
    const float* __restrict__ oW3, const float* __restrict__ ob3,
    const float* __restrict__ oW4, const float* __restrict__ ob4,
    float* __restrict__ out)
{
    int g = blockIdx.x, tid = threadIdx.x;
    int lane = tid & 63, wv = tid >> 6;
    int gs = gstart[g], ge = gstart[g + 1];

    float s0 = 0.f, s1 = 0.f, s2 = 0.f, s3 = 0.f, s4 = 0.f, s5 = 0.f, s6 = 0.f;
    float m0 = -__builtin_inff(), m1 = m0, m2 = m0, m3 = m0, m4 = m0, m5 = m0, m6 = m0;
    for (int n = gs + tid; n < ge; n += 256) {
        const float* xp = x + (size_t)n * 7;
        float v0 = xp[0], v1 = xp[1], v2 = xp[2], v3 = xp[3], v4 = xp[4], v5 = xp[5], v6 = xp[6];
        s0 += v0; s1 += v1; s2 += v2; s3 += v3; s4 += v4; s5 += v5; s6 += v6;
        m0 = fmaxf(m0, v0); m1 = fmaxf(m1, v1); m2 = fmaxf(m2, v2); m3 = fmaxf(m3, v3);
        m4 = fmaxf(m4, v4); m5 = fmaxf(m5, v5); m6 = fmaxf(m6, v6);
    }
    #pragma unroll
    for (int msk = 1; msk < 64; msk <<= 1) {
        s0 += __shfl_xor(s0, msk); s1 += __shfl_xor(s1, msk); s2 += __shfl_xor(s2, msk);
        s3 += __shfl_xor(s3, msk); s4 += __shfl_xor(s4, msk); s5 += __shfl_xor(s5, msk);
        s6 += __shfl_xor(s6, msk);
        m0 = fmaxf(m0, __shfl_xor(m0, msk)); m1 = fmaxf(m1, __shfl_xor(m1, msk));
        m2 = fmaxf(m2, __shfl_xor(m2, msk)); m3 = fmaxf(m3, __shfl_xor(m3, msk));
        m4 = fmaxf(m4, __shfl_xor(m4, msk)); m5 = fmaxf(m5, __shfl_xor(m5, msk));
        m6 = fmaxf(m6, __shfl_xor(m6, msk));
    }
    __shared__ float red[4][14];
    __shared__ float hin[23];
    __shared__ float ha[128];
    __shared__ float hbuf[128];
    if (lane == 0) {
        red[wv][0] = s0; red[wv][1] = s1; red[wv][2] = s2; red[wv][3] = s3;
        red[wv][4] = s4; red[wv][5] = s5; red[wv][6] = s6;
        red[wv][7] = m0; red[wv][8] = m1; red[wv][9] = m2; red[wv][10] = m3;
        red[wv][11] = m4; red[wv][12] = m5; red[wv][13] = m6;
    }
    __syncthreads();
    if (tid < 7) {
        float S = red[0][tid] + red[1][tid] + red[2][tid] + red[3][tid];
        float M = fmaxf(fmaxf(red[0][7 + tid], red[1][7 + tid]),
                        fmaxf(red[2][7 + tid], red[3][7 + tid]));
        float cntf = (float)(ge - gs);
        if (ge == gs) M = 0.f;
        hin[tid] = S;
        hin[7 + tid] = S / fmaxf(cntf, 1.f);
        hin[14 + tid] = M;
    }
    if (tid < 2) hin[21 + tid] = u[g * 2 + tid];
    __syncthreads();

    float h = 0.f;
    if (tid < 128) {
        h = ob1[tid];
        for (int i = 0; i < 23; ++i) h += hin[i] * oW1[i * 128 + tid];
        ha[tid] = fmaxf(h, 0.f);
    }
    __syncthreads();
    if (tid < 128) {
        h = ob2[tid];
        for (int i = 0; i < 128; ++i) h += ha[i] * oW2[i * 128 + tid];
        hbuf[tid] = fmaxf(h, 0.f);
    }
    __syncthreads();
    if (tid < 128) {
        h = ob3[tid];
        for (int i = 0; i < 128; ++i) h += hbuf[i] * oW3[i * 128 + tid];
        ha[tid] = fmaxf(h, 0.f) * oW4[tid];
    }
    __syncthreads();
    if (tid == 0) {
        float acc = ob4[0];
        for (int i = 0; i < 128; ++i) acc += ha[i];
        out[g] = acc;
    }
}

extern "C" void kernel_launch(void* const* d_in, const int* in_sizes, int n_in,
                              void* d_out, int out_size, void* d_ws, size_t ws_size,
                              hipStream_t stream) {
    const float* x         = (const float*)d_in[0];
    const float* edge_attr = (const float*)d_in[1];
    const float* u         = (const float*)d_in[2];
    const float* eW1 = (const float*)d_in[3];
    const float* eb1 = (const float*)d_in[4];
    const float* eW2 = (const float*)d_in[5];
    const float* eb2 = (const float*)d_in[6];
    const float* nW1 = (const float*)d_in[7];
    const float* nb1 = (const float*)d_in[8];
    const float* nW2 = (const float*)d_in[9];
    const float* nb2 = (const float*)d_in[10];
    const float* oW1 = (const float*)d_in[11];
    const float* ob1 = (const float*)d_in[12];
    const float* oW2 = (const float*)d_in[13];
    const float* ob2 = (const float*)d_in[14];
    const float* oW3 = (const float*)d_in[15];
    const float* ob3 = (const float*)d_in[16];
    const float* oW4 = (const float*)d_in[17];
    const float* ob4 = (const float*)d_in[18];
    const int* edge_index = (const int*)d_in[19];
    const int* batch      = (const int*)d_in[20];
    const int* row = edge_index;
    const int* col = edge_index + NE;

    // workspace layout
    float* ws        = (float*)d_ws;
    float* eab       = ws;                                  // E*3   (19.2 MB)
    float* ws_x      = eab + (size_t)NE * 3;                // N*7   (2.8 MB)
    int2*  rc        = (int2*)(ws_x + (size_t)NN * 7);      // E     (12.8 MB)
    float* nred      = (float*)(rc + (size_t)NE);           // N*12  (4.8 MB)
    int*   eidx      = (int*)(nred + (size_t)NN * 12);      // E     (6.4 MB)
    unsigned* cnt    = (unsigned*)(eidx + (size_t)NE);      // N
    unsigned* startv = cnt + NN;                            // N+1
    unsigned* cursor = startv + NN + 1;                     // N
    unsigned* bsum   = cursor + NN;                         // 512
    unsigned* boff   = bsum + 512;                          // 512
    int* gstart      = (int*)(boff + 512);                  // 257
    float* ewt       = (float*)(gstart + 260);              // 2*128*24
    float* nwt       = ewt + 2 * 128 * 24;                  // 2*128*28

    dim3 b256(256);
    dim3 ge_(NE / 256);                 // 6250, exact
    dim3 ge4((NE + 1023) / 1024);       // 1563 (4 edges/thread)
    dim3 gn(NB);                        // 391

    // zero cnt
    zero_kernel<<<(NN + 255) / 256, b256, 0, stream>>>((float*)cnt, NN);

    // CSR + graph-range build
    count_kernel<<<ge_, b256, 0, stream>>>(col, cnt);
    gbound_kernel<<<gn, b256, 0, stream>>>(batch, gstart);
    bsum_kernel<<<gn, b256, 0, stream>>>(cnt, bsum);
    bscan_kernel<<<1, 512, 0, stream>>>(bsum, boff);
    start_kernel<<<gn, b256, 0, stream>>>(cnt, boff, startv, cursor);
    pos_kernel<<<ge_, b256, 0, stream>>>(col, cursor, eidx);
    permute_kernel<<<ge_, b256, 0, stream>>>(eidx, row, col, edge_attr, rc, eab);

    // weight prep
    {
        int t = 2 * 128 * 24 + 2 * 128 * 28;
        prep_kernel<<<(t + 255) / 256, b256, 0, stream>>>(eW1, eb1, eW2, nW1, nb1, nW2, ewt, nwt);
    }

    dim3 gr((NN * 16 + 255) / 256);   // 6250 blocks for reduce

    // ---- layer 0 ----
    edge_kernel<<<ge4, b256, 0, stream>>>(x, eab, rc, ewt, eb2);
    reduce_kernel<<<gr, b256, 0, stream>>>(eab, startv, u, batch, nred);
    nodemlp_kernel<<<NMLP_BLOCKS, b256, 0, stream>>>(x, nred, nwt, nb2, ws_x);

    // ---- layer 1 ----
    edge_kernel<<<ge4, b256, 0, stream>>>(ws_x, eab, rc, ewt + 128 * 24, eb2 + 3);
    reduce_kernel<<<gr, b256, 0, stream>>>(eab, startv, u, batch, nred);
    nodemlp_kernel<<<NMLP_BLOCKS, b256, 0, stream>>>(ws_x, nred, nwt + 128 * 28, nb2 + 7, ws_x);

    // ---- fused pool + head ----
    pool_head_kernel<<<NG, b256, 0, stream>>>(ws_x, gstart, u,
        oW1, ob1, oW2, ob2, oW3, ob3, oW4, ob4, (float*)d_out);
}

// Round 9
// 479.667 us; speedup vs baseline: 1.3518x; 1.3518x over previous
//
#include <hip/hip_runtime.h>

#define NN 100000
#define NE 1600000
#define NG 256
#define NB 391   // ceil(NN/256)

__global__ __launch_bounds__(256) void zero_kernel(float* __restrict__ p, int n) {
    int i = blockIdx.x * 256 + threadIdx.x;
    if (i < n) p[i] = 0.f;
}

// ---------------- CSR build ----------------
// ONE atomic pass: produces per-node counts AND each edge's stable rank.
__global__ __launch_bounds__(256) void rank_kernel(
    const int* __restrict__ col, unsigned* __restrict__ cnt,
    unsigned* __restrict__ rank) {
    int e = blockIdx.x * 256 + threadIdx.x;       // grid covers NE exactly
    rank[e] = atomicAdd(&cnt[col[e]], 1u);
}

// batch is sorted: graph g starts where batch steps past g. No atomics.
__global__ __launch_bounds__(256) void gbound_kernel(
    const int* __restrict__ batch, int* __restrict__ gstart) {
    int n = blockIdx.x * 256 + threadIdx.x;
    if (n >= NN) return;
    int b = batch[n];
    int bp = (n == 0) ? -1 : batch[n - 1];
    for (int g = bp + 1; g <= b; ++g) gstart[g] = n;
    if (n == NN - 1) {
        for (int g = b + 1; g <= NG; ++g) gstart[g] = NN;
    }
}

__global__ __launch_bounds__(256) void bsum_kernel(
    const unsigned* __restrict__ cnt, unsigned* __restrict__ bsum) {
    __shared__ unsigned sm[256];
    int i = blockIdx.x * 256 + threadIdx.x;
    sm[threadIdx.x] = (i < NN) ? cnt[i] : 0u;
    __syncthreads();
    for (int s = 128; s > 0; s >>= 1) {
        if (threadIdx.x < s) sm[threadIdx.x] += sm[threadIdx.x + s];
        __syncthreads();
    }
    if (threadIdx.x == 0) bsum[blockIdx.x] = sm[0];
}

__global__ __launch_bounds__(512) void bscan_kernel(
    const unsigned* __restrict__ bsum, unsigned* __restrict__ boff) {
    __shared__ unsigned a[512], b[512];
    int t = threadIdx.x;
    a[t] = (t < NB) ? bsum[t] : 0u;
    __syncthreads();
    unsigned* src = a; unsigned* dst = b;
    for (int off = 1; off < 512; off <<= 1) {
        unsigned v = src[t];
        if (t >= off) v += src[t - off];
        dst[t] = v;
        __syncthreads();
        unsigned* tmp = src; src = dst; dst = tmp;
    }
    if (t < NB) boff[t] = (t == 0) ? 0u : src[t - 1];
}

__global__ __launch_bounds__(256) void start_kernel(
    const unsigned* __restrict__ cnt, const unsigned* __restrict__ boff,
    unsigned* __restrict__ start) {
    __shared__ unsigned a[256], b[256];
    int t = threadIdx.x;
    int i = blockIdx.x * 256 + t;
    unsigned v = (i < NN) ? cnt[i] : 0u;
    a[t] = v;
    __syncthreads();
    unsigned* src = a; unsigned* dst = b;
    for (int off = 1; off < 256; off <<= 1) {
        unsigned x = src[t];
        if (t >= off) x += src[t - off];
        dst[t] = x;
        __syncthreads();
        unsigned* tmp = src; src = dst; dst = tmp;
    }
    unsigned excl = src[t] - v;
    unsigned st = boff[blockIdx.x] + excl;
    if (i < NN) {
        start[i] = st;
        if (i == NN - 1) start[NN] = st + v;
    }
}

// atomic-free scatter: slot = start[col] + rank. Random 20B write only.
__global__ __launch_bounds__(256) void scatter_kernel(
    const int* __restrict__ row, const int* __restrict__ col,
    const float* __restrict__ ea,
    const unsigned* __restrict__ start, const unsigned* __restrict__ rank,
    int2* __restrict__ rc, float* __restrict__ eab) {
    int e = blockIdx.x * 256 + threadIdx.x;       // grid covers NE exactly
    int c = col[e];
    unsigned t = start[c] + rank[e];
    rc[t] = make_int2(row[e], c);
    eab[(size_t)t * 3 + 0] = ea[(size_t)e * 3 + 0];
    eab[(size_t)t * 3 + 1] = ea[(size_t)e * 3 + 1];
    eab[(size_t)t * 3 + 2] = ea[(size_t)e * 3 + 2];
}

// ---------------- weight prep (padded rows) ----------------
//   ewt: 2 x 128 x 24  [W1[0..16][j], b1[j], W2[j][0..2], pad x3]
//   nwt: 2 x 128 x 28  [W1[0..17][j], b1[j], W2[j][0..6], pad x2]
__global__ __launch_bounds__(256) void prep_kernel(
    const float* __restrict__ eW1, const float* __restrict__ eb1, const float* __restrict__ eW2,
    const float* __restrict__ nW1, const float* __restrict__ nb1, const float* __restrict__ nW2,
    float* __restrict__ ewt, float* __restrict__ nwt)
{
    int t = blockIdx.x * 256 + threadIdx.x;
    const int ESZ = 2 * 128 * 24;
    const int NSZ = 2 * 128 * 28;
    if (t < ESZ) {
        int l = t / (128 * 24), rest = t % (128 * 24), j = rest / 24, i = rest % 24;
        float v = 0.f;
        if (i < 17)       v = eW1[l * 17 * 128 + i * 128 + j];
        else if (i == 17) v = eb1[l * 128 + j];
        else if (i < 21)  v = eW2[l * 128 * 3 + j * 3 + (i - 18)];
        ewt[t] = v;
    } else if (t < ESZ + NSZ) {
        int q = t - ESZ;
        int l = q / (128 * 28), rest = q % (128 * 28), j = rest / 28, i = rest % 28;
        float v = 0.f;
        if (i < 18)       v = nW1[l * 18 * 128 + i * 128 + j];
        else if (i == 18) v = nb1[l * 128 + j];
        else if (i < 26)  v = nW2[l * 128 * 7 + j * 7 + (i - 19)];
        nwt[q] = v;
    }
}

// ---------------- edge MLP: 4 edges/thread, scalar weights ----------------
__global__ __launch_bounds__(256) void edge_kernel(
    const float* __restrict__ x, float* eab,
    const int2* __restrict__ rc,
    const float* __restrict__ wt, const float* __restrict__ b2)
{
    int base = blockIdx.x * 1024 + threadIdx.x;
    int tt[4];
    bool ok[4];
    float in[4][17];

    #pragma unroll
    for (int k = 0; k < 4; ++k) {
        int t = base + k * 256;
        ok[k] = (t < NE);
        tt[k] = ok[k] ? t : 0;
        int2 p = rc[tt[k]];
        const float* xr = x + (size_t)p.x * 7;
        const float* xc = x + (size_t)p.y * 7;
        #pragma unroll
        for (int i = 0; i < 7; ++i) in[k][i] = xr[i];
        #pragma unroll
        for (int i = 0; i < 7; ++i) in[k][7 + i] = xc[i];
        #pragma unroll
        for (int i = 0; i < 3; ++i) in[k][14 + i] = eab[(size_t)tt[k] * 3 + i];
    }

    asm volatile("" : "+v"(in[0][0]), "+v"(in[0][1]), "+v"(in[0][2]), "+v"(in[0][3]),
                      "+v"(in[0][4]), "+v"(in[0][5]), "+v"(in[0][6]), "+v"(in[0][7]),
                      "+v"(in[0][8]), "+v"(in[0][9]), "+v"(in[0][10]), "+v"(in[0][11]),
                      "+v"(in[0][12]), "+v"(in[0][13]), "+v"(in[0][14]), "+v"(in[0][15]),
                      "+v"(in[0][16]));
    asm volatile("" : "+v"(in[1][0]), "+v"(in[1][1]), "+v"(in[1][2]), "+v"(in[1][3]),
                      "+v"(in[1][4]), "+v"(in[1][5]), "+v"(in[1][6]), "+v"(in[1][7]),
                      "+v"(in[1][8]), "+v"(in[1][9]), "+v"(in[1][10]), "+v"(in[1][11]),
                      "+v"(in[1][12]), "+v"(in[1][13]), "+v"(in[1][14]), "+v"(in[1][15]),
                      "+v"(in[1][16]));
    asm volatile("" : "+v"(in[2][0]), "+v"(in[2][1]), "+v"(in[2][2]), "+v"(in[2][3]),
                      "+v"(in[2][4]), "+v"(in[2][5]), "+v"(in[2][6]), "+v"(in[2][7]),
                      "+v"(in[2][8]), "+v"(in[2][9]), "+v"(in[2][10]), "+v"(in[2][11]),
                      "+v"(in[2][12]), "+v"(in[2][13]), "+v"(in[2][14]), "+v"(in[2][15]),
                      "+v"(in[2][16]));
    asm volatile("" : "+v"(in[3][0]), "+v"(in[3][1]), "+v"(in[3][2]), "+v"(in[3][3]),
                      "+v"(in[3][4]), "+v"(in[3][5]), "+v"(in[3][6]), "+v"(in[3][7]),
                      "+v"(in[3][8]), "+v"(in[3][9]), "+v"(in[3][10]), "+v"(in[3][11]),
                      "+v"(in[3][12]), "+v"(in[3][13]), "+v"(in[3][14]), "+v"(in[3][15]),
                      "+v"(in[3][16]));

    float acc[4][3];
    #pragma unroll
    for (int k = 0; k < 4; ++k) { acc[k][0] = 0.f; acc[k][1] = 0.f; acc[k][2] = 0.f; }

    #pragma unroll 4
    for (int j = 0; j < 128; ++j) {
        const float* wr = wt + __builtin_amdgcn_readfirstlane(j * 24);
        float w[21];
        #pragma unroll
        for (int i = 0; i < 21; ++i) w[i] = wr[i];
        float h0[4], h1[4];
        #pragma unroll
        for (int k = 0; k < 4; ++k) { h0[k] = w[17]; h1[k] = 0.f; }
        #pragma unroll
        for (int k = 0; k < 4; ++k) {
            h0[k] += in[k][0] * w[0];   h1[k] += in[k][1] * w[1];
            h0[k] += in[k][2] * w[2];   h1[k] += in[k][3] * w[3];
            h0[k] += in[k][4] * w[4];   h1[k] += in[k][5] * w[5];
            h0[k] += in[k][6] * w[6];   h1[k] += in[k][7] * w[7];
            h0[k] += in[k][8] * w[8];   h1[k] += in[k][9] * w[9];
            h0[k] += in[k][10] * w[10]; h1[k] += in[k][11] * w[11];
            h0[k] += in[k][12] * w[12]; h1[k] += in[k][13] * w[13];
            h0[k] += in[k][14] * w[14]; h1[k] += in[k][15] * w[15];
            h0[k] += in[k][16] * w[16];
        }
        #pragma unroll
        for (int k = 0; k < 4; ++k) {
            float h = fmaxf(h0[k] + h1[k], 0.f);
            acc[k][0] += h * w[18];
            acc[k][1] += h * w[19];
            acc[k][2] += h * w[20];
        }
    }

    float bb0 = b2[0], bb1 = b2[1], bb2 = b2[2];
    #pragma unroll
    for (int k = 0; k < 4; ++k) {
        if (ok[k]) {
            eab[(size_t)tt[k] * 3 + 0] = acc[k][0] + bb0;
            eab[(size_t)tt[k] * 3 + 1] = acc[k][1] + bb1;
            eab[(size_t)tt[k] * 3 + 2] = acc[k][2] + bb2;
        }
    }
}

// ---------------- segment reduce: 16 lanes per node ----------------
__global__ __launch_bounds__(256) void reduce_kernel(
    const float* __restrict__ eab, const unsigned* __restrict__ start,
    const float* __restrict__ u, const int* __restrict__ batch,
    float* __restrict__ nred)
{
    int gid = blockIdx.x * 256 + threadIdx.x;
    int n = gid >> 4, sub = gid & 15;
    if (n >= NN) return;
    unsigned sbeg = start[n], send = start[n + 1];

    float s0 = 0.f, s1 = 0.f, s2 = 0.f;
    float m0 = -__builtin_inff(), m1 = -__builtin_inff(), m2 = -__builtin_inff();
    for (unsigned k = sbeg + sub; k < send; k += 16) {
        float v0 = eab[(size_t)k * 3 + 0];
        float v1 = eab[(size_t)k * 3 + 1];
        float v2 = eab[(size_t)k * 3 + 2];
        s0 += v0; s1 += v1; s2 += v2;
        m0 = fmaxf(m0, v0); m1 = fmaxf(m1, v1); m2 = fmaxf(m2, v2);
    }
    #pragma unroll
    for (int msk = 1; msk < 16; msk <<= 1) {
        s0 += __shfl_xor(s0, msk, 16);
        s1 += __shfl_xor(s1, msk, 16);
        s2 += __shfl_xor(s2, msk, 16);
        m0 = fmaxf(m0, __shfl_xor(m0, msk, 16));
        m1 = fmaxf(m1, __shfl_xor(m1, msk, 16));
        m2 = fmaxf(m2, __shfl_xor(m2, msk, 16));
    }
    if (sub == 0) {
        float deg = (float)(send - sbeg);
        if (send == sbeg) { m0 = 0.f; m1 = 0.f; m2 = 0.f; }
        float inv = 1.f / fmaxf(deg, 1.f);
        int b = batch[n];
        float* o = nred + (size_t)n * 12;
        o[0] = s0; o[1] = s1; o[2] = s2;
        o[3] = m0; o[4] = m1; o[5] = m2;
        o[6] = s0 * inv; o[7] = s1 * inv; o[8] = s2 * inv;
        o[9] = u[b * 2 + 0]; o[10] = u[b * 2 + 1];
    }
}

// ---------------- node MLP: wave-per-node, weight-stationary ----------------
#define NMLP_BLOCKS 1024
#define NMLP_WAVES (NMLP_BLOCKS * 4)
__global__ __launch_bounds__(256, 4) void nodemlp_kernel(
    const float* x_in, const float* __restrict__ nred,
    const float* __restrict__ wt, const float* __restrict__ b2,
    float* x_out)
{
    int lane = threadIdx.x & 63;
    int wid = (blockIdx.x * 256 + threadIdx.x) >> 6;

    const float* ra = wt + lane * 28;
    const float* rb = wt + (lane + 64) * 28;
    float a0 = ra[0], a1 = ra[1], a2 = ra[2], a3 = ra[3], a4 = ra[4], a5 = ra[5],
          a6 = ra[6], a7 = ra[7], a8 = ra[8], a9 = ra[9], a10 = ra[10], a11 = ra[11],
          a12 = ra[12], a13 = ra[13], a14 = ra[14], a15 = ra[15], a16 = ra[16], a17 = ra[17],
          ab = ra[18], p0 = ra[19], p1 = ra[20], p2 = ra[21], p3 = ra[22], p4 = ra[23],
          p5 = ra[24], p6 = ra[25];
    float b0 = rb[0], b1 = rb[1], b2_ = rb[2], b3 = rb[3], b4 = rb[4], b5 = rb[5],
          b6 = rb[6], b7 = rb[7], b8 = rb[8], b9 = rb[9], b10 = rb[10], b11 = rb[11],
          b12 = rb[12], b13 = rb[13], b14 = rb[14], b15 = rb[15], b16 = rb[16], b17 = rb[17],
          bb = rb[18], q0 = rb[19], q1 = rb[20], q2 = rb[21], q3 = rb[22], q4 = rb[23],
          q5 = rb[24], q6 = rb[25];

    asm volatile("" : "+v"(a0), "+v"(a1), "+v"(a2), "+v"(a3), "+v"(a4), "+v"(a5),
                      "+v"(a6), "+v"(a7), "+v"(a8), "+v"(a9), "+v"(a10), "+v"(a11),
                      "+v"(a12), "+v"(a13), "+v"(a14), "+v"(a15), "+v"(a16), "+v"(a17),
                      "+v"(ab), "+v"(p0), "+v"(p1), "+v"(p2), "+v"(p3), "+v"(p4),
                      "+v"(p5), "+v"(p6));
    asm volatile("" : "+v"(b0), "+v"(b1), "+v"(b2_), "+v"(b3), "+v"(b4), "+v"(b5),
                      "+v"(b6), "+v"(b7), "+v"(b8), "+v"(b9), "+v"(b10), "+v"(b11),
                      "+v"(b12), "+v"(b13), "+v"(b14), "+v"(b15), "+v"(b16), "+v"(b17),
                      "+v"(bb), "+v"(q0), "+v"(q1), "+v"(q2), "+v"(q3), "+v"(q4),
                      "+v"(q5), "+v"(q6));

    float B0 = b2[0], B1 = b2[1], B2 = b2[2], B3 = b2[3], B4 = b2[4], B5 = b2[5], B6 = b2[6];

    const int nper = (NN + NMLP_WAVES - 1) / NMLP_WAVES;   // 25
    int n0 = wid * nper;
    int n1 = n0 + nper; if (n1 > NN) n1 = NN;

    #pragma unroll 2
    for (int n = n0; n < n1; ++n) {
        int nu = __builtin_amdgcn_readfirstlane(n);
        const float* xp = x_in + (size_t)nu * 7;
        const float* rp = nred + (size_t)nu * 12;
        float i0 = xp[0], i1 = xp[1], i2 = xp[2], i3 = xp[3], i4 = xp[4], i5 = xp[5], i6 = xp[6];
        float s0 = rp[0], s1 = rp[1], s2 = rp[2];
        float m0 = rp[3], m1 = rp[4], m2 = rp[5];
        float e0 = rp[6], e1 = rp[7], e2 = rp[8];
        float u0 = rp[9], u1 = rp[10];

        float ha = ab, hb = bb;
        ha += i0 * a0;  hb += i0 * b0;
        ha += i1 * a1;  hb += i1 * b1;
        ha += i2 * a2;  hb += i2 * b2_;
        ha += i3 * a3;  hb += i3 * b3;
        ha += i4 * a4;  hb += i4 * b4;
        ha += i5 * a5;  hb += i5 * b5;
        ha += i6 * a6;  hb += i6 * b6;
        ha += s0 * a7;  hb += s0 * b7;
        ha += s1 * a8;  hb += s1 * b8;
        ha += s2 * a9;  hb += s2 * b9;
        ha += m0 * a10; hb += m0 * b10;
        ha += m1 * a11; hb += m1 * b11;
        ha += m2 * a12; hb += m2 * b12;
        ha += e0 * a13; hb += e0 * b13;
        ha += e1 * a14; hb += e1 * b14;
        ha += e2 * a15; hb += e2 * b15;
        ha += u0 * a16; hb += u0 * b16;
        ha += u1 * a17; hb += u1 * b17;
        ha = fmaxf(ha, 0.f); hb = fmaxf(hb, 0.f);

        float c0 = ha * p0 + hb * q0;
        float c1 = ha * p1 + hb * q1;
        float c2 = ha * p2 + hb * q2;
        float c3 = ha * p3 + hb * q3;
        float c4 = ha * p4 + hb * q4;
        float c5 = ha * p5 + hb * q5;
        float c6 = ha * p6 + hb * q6;
        #pragma unroll
        for (int msk = 1; msk < 64; msk <<= 1) {
            c0 += __shfl_xor(c0, msk);
            c1 += __shfl_xor(c1, msk);
            c2 += __shfl_xor(c2, msk);
            c3 += __shfl_xor(c3, msk);
            c4 += __shfl_xor(c4, msk);
            c5 += __shfl_xor(c5, msk);
            c6 += __shfl_xor(c6, msk);
        }
        float o = c0 + B0;
        if (lane == 1) o = c1 + B1;
        if (lane == 2) o = c2 + B2;
        if (lane == 3) o = c3 + B3;
        if (lane == 4) o = c4 + B4;
        if (lane == 5) o = c5 + B5;
        if (lane == 6) o = c6 + B6;
        if (lane < 7) x_out[(size_t)nu * 7 + lane] = o;
    }
}

// ---------------- fused graph pool + output head (block per graph) ----------
__global__ __launch_bounds__(256) void pool_head_kernel(
    const float* __restrict__ x, const int* __restrict__ gstart,
    const float* __restrict__ u,
    const float* __restrict__ oW1, const float* __restrict__ ob1,
    const float* __restrict__ oW2, const float* __restrict__ ob2,
    const float* __restrict__ oW3, const float* __restrict__ ob3,
    const float* __restrict__ oW4, const float* __restrict__ ob4,
    float* __restrict__ out)
{
    int g = blockIdx.x, tid = threadIdx.x;
    int lane = tid & 63, wv = tid >> 6;
    int gs = gstart[g], ge = gstart[g + 1];

    float s0 = 0.f, s1 = 0.f, s2 = 0.f, s3 = 0.f, s4 = 0.f, s5 = 0.f, s6 = 0.f;
    float m0 = -__builtin_inff(), m1 = m0, m2 = m0, m3 = m0, m4 = m0, m5 = m0, m6 = m0;
    for (int n = gs + tid; n < ge; n += 256) {
        const float* xp = x + (size_t)n * 7;
        float v0 = xp[0], v1 = xp[1], v2 = xp[2], v3 = xp[3], v4 = xp[4], v5 = xp[5], v6 = xp[6];
        s0 += v0; s1 += v1; s2 += v2; s3 += v3; s4 += v4; s5 += v5; s6 += v6;
        m0 = fmaxf(m0, v0); m1 = fmaxf(m1, v1); m2 = fmaxf(m2, v2); m3 = fmaxf(m3, v3);
        m4 = fmaxf(m4, v4); m5 = fmaxf(m5, v5); m6 = fmaxf(m6, v6);
    }
    #pragma unroll
    for (int msk = 1; msk < 64; msk <<= 1) {
        s0 += __shfl_xor(s0, msk); s1 += __shfl_xor(s1, msk); s2 += __shfl_xor(s2, msk);
        s3 += __shfl_xor(s3, msk); s4 += __shfl_xor(s4, msk); s5 += __shfl_xor(s5, msk);
        s6 += __shfl_xor(s6, msk);
        m0 = fmaxf(m0, __shfl_xor(m0, msk)); m1 = fmaxf(m1, __shfl_xor(m1, msk));
        m2 = fmaxf(m2, __shfl_xor(m2, msk)); m3 = fmaxf(m3, __shfl_xor(m3, msk));
        m4 = fmaxf(m4, __shfl_xor(m4, msk)); m5 = fmaxf(m5, __shfl_xor(m5, msk));
        m6 = fmaxf(m6, __shfl_xor(m6, msk));
    }
    __shared__ float red[4][14];
    __shared__ float hin[23];
    __shared__ float ha[128];
    __shared__ float hbuf[128];
    if (lane == 0) {
        red[wv][0] = s0; red[wv][1] = s1; red[wv][2] = s2; red[wv][3] = s3;
        red[wv][4] = s4; red[wv][5] = s5; red[wv][6] = s6;
        red[wv][7] = m0; red[wv][8] = m1; red[wv][9] = m2; red[wv][10] = m3;
        red[wv][11] = m4; red[wv][12] = m5; red[wv][13] = m6;
    }
    __syncthreads();
    if (tid < 7) {
        float S = red[0][tid] + red[1][tid] + red[2][tid] + red[3][tid];
        float M = fmaxf(fmaxf(red[0][7 + tid], red[1][7 + tid]),
                        fmaxf(red[2][7 + tid], red[3][7 + tid]));
        float cntf = (float)(ge - gs);
        if (ge == gs) M = 0.f;
        hin[tid] = S;
        hin[7 + tid] = S / fmaxf(cntf, 1.f);
        hin[14 + tid] = M;
    }
    if (tid < 2) hin[21 + tid] = u[g * 2 + tid];
    __syncthreads();

    float h = 0.f;
    if (tid < 128) {
        h = ob1[tid];
        for (int i = 0; i < 23; ++i) h += hin[i] * oW1[i * 128 + tid];
        ha[tid] = fmaxf(h, 0.f);
    }
    __syncthreads();
    if (tid < 128) {
        h = ob2[tid];
        for (int i = 0; i < 128; ++i) h += ha[i] * oW2[i * 128 + tid];
        hbuf[tid] = fmaxf(h, 0.f);
    }
    __syncthreads();
    if (tid < 128) {
        h = ob3[tid];
        for (int i = 0; i < 128; ++i) h += hbuf[i] * oW3[i * 128 + tid];
        ha[tid] = fmaxf(h, 0.f) * oW4[tid];
    }
    __syncthreads();
    if (tid == 0) {
        float acc = ob4[0];
        for (int i = 0; i < 128; ++i) acc += ha[i];
        out[g] = acc;
    }
}

extern "C" void kernel_launch(void* const* d_in, const int* in_sizes, int n_in,
                              void* d_out, int out_size, void* d_ws, size_t ws_size,
                              hipStream_t stream) {
    const float* x         = (const float*)d_in[0];
    const float* edge_attr = (const float*)d_in[1];
    const float* u         = (const float*)d_in[2];
    const float* eW1 = (const float*)d_in[3];
    const float* eb1 = (const float*)d_in[4];
    const float* eW2 = (const float*)d_in[5];
    const float* eb2 = (const float*)d_in[6];
    const float* nW1 = (const float*)d_in[7];
    const float* nb1 = (const float*)d_in[8];
    const float* nW2 = (const float*)d_in[9];
    const float* nb2 = (const float*)d_in[10];
    const float* oW1 = (const float*)d_in[11];
    const float* ob1 = (const float*)d_in[12];
    const float* oW2 = (const float*)d_in[13];
    const float* ob2 = (const float*)d_in[14];
    const float* oW3 = (const float*)d_in[15];
    const float* ob3 = (const float*)d_in[16];
    const float* oW4 = (const float*)d_in[17];
    const float* ob4 = (const float*)d_in[18];
    const int* edge_index = (const int*)d_in[19];
    const int* batch      = (const int*)d_in[20];
    const int* row = edge_index;
    const int* col = edge_index + NE;

    // workspace layout
    float* ws        = (float*)d_ws;
    float* eab       = ws;                                  // E*3   (19.2 MB)
    float* ws_x      = eab + (size_t)NE * 3;                // N*7   (2.8 MB)
    int2*  rc        = (int2*)(ws_x + (size_t)NN * 7);      // E     (12.8 MB)
    float* nred      = (float*)(rc + (size_t)NE);           // N*12  (4.8 MB)
    unsigned* rank   = (unsigned*)(nred + (size_t)NN * 12); // E     (6.4 MB)
    unsigned* cnt    = rank + (size_t)NE;                   // N
    unsigned* startv = cnt + NN;                            // N+1
    unsigned* bsum   = startv + NN + 1;                     // 512
    unsigned* boff   = bsum + 512;                          // 512
    int* gstart      = (int*)(boff + 512);                  // 257
    float* ewt       = (float*)(gstart + 260);              // 2*128*24
    float* nwt       = ewt + 2 * 128 * 24;                  // 2*128*28

    dim3 b256(256);
    dim3 ge_(NE / 256);                 // 6250, exact
    dim3 ge4((NE + 1023) / 1024);       // 1563 (4 edges/thread)
    dim3 gn(NB);                        // 391

    // zero cnt
    zero_kernel<<<(NN + 255) / 256, b256, 0, stream>>>((float*)cnt, NN);

    // CSR + graph-range build: ONE atomic pass (rank), then scan, then
    // atomic-free scatter.
    rank_kernel<<<ge_, b256, 0, stream>>>(col, cnt, rank);
    gbound_kernel<<<gn, b256, 0, stream>>>(batch, gstart);
    bsum_kernel<<<gn, b256, 0, stream>>>(cnt, bsum);
    bscan_kernel<<<1, 512, 0, stream>>>(bsum, boff);
    start_kernel<<<gn, b256, 0, stream>>>(cnt, boff, startv);
    scatter_kernel<<<ge_, b256, 0, stream>>>(row, col, edge_attr, startv, rank, rc, eab);

    // weight prep
    {
        int t = 2 * 128 * 24 + 2 * 128 * 28;
        prep_kernel<<<(t + 255) / 256, b256, 0, stream>>>(eW1, eb1, eW2, nW1, nb1, nW2, ewt, nwt);
    }

    dim3 gr((NN * 16 + 255) / 256);   // 6250 blocks for reduce

    // ---- layer 0 ----
    edge_kernel<<<ge4, b256, 0, stream>>>(x, eab, rc, ewt, eb2);
    reduce_kernel<<<gr, b256, 0, stream>>>(eab, startv, u, batch, nred);
    nodemlp_kernel<<<NMLP_BLOCKS, b256, 0, stream>>>(x, nred, nwt, nb2, ws_x);

    // ---- layer 1 ----
    edge_kernel<<<ge4, b256, 0, stream>>>(ws_x, eab, rc, ewt + 128 * 24, eb2 + 3);
    reduce_kernel<<<gr, b256, 0, stream>>>(eab, startv, u, batch, nred);
    nodemlp_kernel<<<NMLP_BLOCKS, b256, 0, stream>>>(ws_x, nred, nwt + 128 * 28, nb2 + 7, ws_x);

    // ---- fused pool + head ----
    pool_head_kernel<<<NG, b256, 0, stream>>>(ws_x, gstart, u,
        oW1, ob1, oW2, ob2, oW3, ob3, oW4, ob4, (float*)d_out);
}

// Round 10
// 426.969 us; speedup vs baseline: 1.5187x; 1.1234x over previous
//
#include <hip/hip_runtime.h>

#define NN 100000
#define NE 1600000
#define NG 256
#define NB 391   // ceil(NN/256)

typedef __attribute__((ext_vector_type(8))) short short8v;
typedef __attribute__((ext_vector_type(4))) float float4v;

__device__ __forceinline__ unsigned short f2bf(float f) {
    unsigned u = __float_as_uint(f);
    return (unsigned short)((u + 0x7FFFu + ((u >> 16) & 1u)) >> 16);  // RNE
}

__global__ __launch_bounds__(256) void zero_kernel(float* __restrict__ p, int n) {
    int i = blockIdx.x * 256 + threadIdx.x;
    if (i < n) p[i] = 0.f;
}

// ---------------- CSR build ----------------
// ONE atomic pass: per-node counts AND each edge's stable rank.
__global__ __launch_bounds__(256) void rank_kernel(
    const int* __restrict__ col, unsigned* __restrict__ cnt,
    unsigned* __restrict__ rank) {
    int e = blockIdx.x * 256 + threadIdx.x;       // grid covers NE exactly
    rank[e] = atomicAdd(&cnt[col[e]], 1u);
}

// batch is sorted: graph boundaries by step detection. No atomics.
__global__ __launch_bounds__(256) void gbound_kernel(
    const int* __restrict__ batch, int* __restrict__ gstart) {
    int n = blockIdx.x * 256 + threadIdx.x;
    if (n >= NN) return;
    int b = batch[n];
    int bp = (n == 0) ? -1 : batch[n - 1];
    for (int g = bp + 1; g <= b; ++g) gstart[g] = n;
    if (n == NN - 1) {
        for (int g = b + 1; g <= NG; ++g) gstart[g] = NN;
    }
}

__global__ __launch_bounds__(256) void bsum_kernel(
    const unsigned* __restrict__ cnt, unsigned* __restrict__ bsum) {
    __shared__ unsigned sm[256];
    int i = blockIdx.x * 256 + threadIdx.x;
    sm[threadIdx.x] = (i < NN) ? cnt[i] : 0u;
    __syncthreads();
    for (int s = 128; s > 0; s >>= 1) {
        if (threadIdx.x < s) sm[threadIdx.x] += sm[threadIdx.x + s];
        __syncthreads();
    }
    if (threadIdx.x == 0) bsum[blockIdx.x] = sm[0];
}

__global__ __launch_bounds__(512) void bscan_kernel(
    const unsigned* __restrict__ bsum, unsigned* __restrict__ boff) {
    __shared__ unsigned a[512], b[512];
    int t = threadIdx.x;
    a[t] = (t < NB) ? bsum[t] : 0u;
    __syncthreads();
    unsigned* src = a; unsigned* dst = b;
    for (int off = 1; off < 512; off <<= 1) {
        unsigned v = src[t];
        if (t >= off) v += src[t - off];
        dst[t] = v;
        __syncthreads();
        unsigned* tmp = src; src = dst; dst = tmp;
    }
    if (t < NB) boff[t] = (t == 0) ? 0u : src[t - 1];
}

__global__ __launch_bounds__(256) void start_kernel(
    const unsigned* __restrict__ cnt, const unsigned* __restrict__ boff,
    unsigned* __restrict__ start) {
    __shared__ unsigned a[256], b[256];
    int t = threadIdx.x;
    int i = blockIdx.x * 256 + t;
    unsigned v = (i < NN) ? cnt[i] : 0u;
    a[t] = v;
    __syncthreads();
    unsigned* src = a; unsigned* dst = b;
    for (int off = 1; off < 256; off <<= 1) {
        unsigned x = src[t];
        if (t >= off) x += src[t - off];
        dst[t] = x;
        __syncthreads();
        unsigned* tmp = src; src = dst; dst = tmp;
    }
    unsigned excl = src[t] - v;
    unsigned st = boff[blockIdx.x] + excl;
    if (i < NN) {
        start[i] = st;
        if (i == NN - 1) start[NN] = st + v;
    }
}

// atomic-free scatter: slot = start[col] + rank.
__global__ __launch_bounds__(256) void scatter_kernel(
    const int* __restrict__ row, const int* __restrict__ col,
    const float* __restrict__ ea,
    const unsigned* __restrict__ start, const unsigned* __restrict__ rank,
    int2* __restrict__ rc, float* __restrict__ eab) {
    int e = blockIdx.x * 256 + threadIdx.x;       // grid covers NE exactly
    int c = col[e];
    unsigned t = start[c] + rank[e];
    rc[t] = make_int2(row[e], c);
    eab[(size_t)t * 3 + 0] = ea[(size_t)e * 3 + 0];
    eab[(size_t)t * 3 + 1] = ea[(size_t)e * 3 + 1];
    eab[(size_t)t * 3 + 2] = ea[(size_t)e * 3 + 2];
}

// ---------------- weight prep ----------------
// ewf: per-lane pre-swizzled bf16 B-frags of W1 (padded K 17->32):
//   [layer][t=0..7][lane=0..63][i=0..7], value = W1[k][n], k=(lane>>4)*8+i,
//   n = t*16 + (lane&15), zero for k>=17.   (sigma shared with A-frags)
// w2f: [layer][lane][t][c] = W2[t*16+(lane&15)][c]   (fp32)
// b1f: [layer][lane][t]    = b1[t*16+(lane&15)]      (fp32)
// nwt: node-MLP rows as before.
__global__ __launch_bounds__(256) void prep_kernel(
    const float* __restrict__ eW1, const float* __restrict__ eb1, const float* __restrict__ eW2,
    const float* __restrict__ nW1, const float* __restrict__ nb1, const float* __restrict__ nW2,
    short* __restrict__ ewf, float* __restrict__ w2f, float* __restrict__ b1f,
    float* __restrict__ nwt)
{
    int t = blockIdx.x * 256 + threadIdx.x;
    const int EWF = 2 * 4096;      // 8192 shorts
    const int W2F = 2 * 1536;      // 3072 floats
    const int B1F = 2 * 512;       // 1024 floats
    const int NWT = 2 * 128 * 28;  // 7168 floats
    if (t < EWF) {
        int layer = t >> 12, r = t & 4095;
        int tt = r >> 9, r2 = r & 511;
        int l = r2 >> 3, i = r2 & 7;
        int kk = ((l >> 4) << 3) + i;
        int n = tt * 16 + (l & 15);
        float v = (kk < 17) ? eW1[layer * 17 * 128 + kk * 128 + n] : 0.f;
        ewf[t] = (short)f2bf(v);
    } else if (t < EWF + W2F) {
        int q = t - EWF;
        int layer = q / 1536, r = q % 1536;
        int l = r / 24, r2 = r % 24;
        int tt = r2 / 3, c = r2 % 3;
        int k = tt * 16 + (l & 15);
        w2f[q] = eW2[layer * 384 + k * 3 + c];
    } else if (t < EWF + W2F + B1F) {
        int q = t - EWF - W2F;
        int layer = q / 512, r = q % 512;
        int l = r / 8, tt = r % 8;
        b1f[q] = eb1[layer * 128 + tt * 16 + (l & 15)];
    } else if (t < EWF + W2F + B1F + NWT) {
        int q = t - EWF - W2F - B1F;
        int l = q / (128 * 28), rest = q % (128 * 28), j = rest / 28, i = rest % 28;
        float v = 0.f;
        if (i < 18)       v = nW1[l * 18 * 128 + i * 128 + j];
        else if (i == 18) v = nb1[l * 128 + j];
        else if (i < 26)  v = nW2[l * 128 * 7 + j * 7 + (i - 19)];
        nwt[q] = v;
    }
}

// ---------------- edge MLP via MFMA bf16 ----------------
// One wave = one 16-edge tile (grid-stride). GEMM1 (17pad32 -> 128) on the
// matrix pipe; relu+bias in C-frags; GEMM2 (128 -> 3) in fp32 VALU with a
// width-16 butterfly. NE = 16*100000 exactly -> no bounds checks.
__global__ __launch_bounds__(256) void edge_kernel(
    const float* __restrict__ x, float* eab,
    const int2* __restrict__ rc,
    const short* __restrict__ ewf, const float* __restrict__ w2f,
    const float* __restrict__ b1f, const float* __restrict__ b2)
{
    int lane = threadIdx.x & 63;
    int l15 = lane & 15, lg = lane >> 4;
    int wid = (blockIdx.x * 256 + threadIdx.x) >> 6;
    int nwaves = gridDim.x * 4;

    // loop-invariant per-lane tables
    short8v B1[8];
    #pragma unroll
    for (int t = 0; t < 8; ++t)
        B1[t] = *(const short8v*)(ewf + (t * 64 + lane) * 8);
    float w2a[8], w2b[8], w2c[8], b1v[8];
    #pragma unroll
    for (int t = 0; t < 8; ++t) {
        w2a[t] = w2f[lane * 24 + t * 3 + 0];
        w2b[t] = w2f[lane * 24 + t * 3 + 1];
        w2c[t] = w2f[lane * 24 + t * 3 + 2];
        b1v[t] = b1f[lane * 8 + t];
    }
    float bb0 = b2[0], bb1 = b2[1], bb2 = b2[2];

    const int NT = NE / 16;    // 100000 tiles
    for (int tile = wid; tile < NT; tile += nwaves) {
        int s = tile * 16 + l15;
        int2 p = rc[s];
        const float* xr = x + (size_t)p.x * 7;
        const float* xc = x + (size_t)p.y * 7;
        const float* ep = eab + (size_t)s * 3;

        // A-frag: row = l15 (edge in tile), k = lg*8 + i (same sigma as B)
        float av0 = 0.f, av1 = 0.f, av2 = 0.f, av3 = 0.f,
              av4 = 0.f, av5 = 0.f, av6 = 0.f, av7 = 0.f;
        if (lg == 0) {          // k 0..7 : xr[0..6], xc[0]
            av0 = xr[0]; av1 = xr[1]; av2 = xr[2]; av3 = xr[3];
            av4 = xr[4]; av5 = xr[5]; av6 = xr[6]; av7 = xc[0];
        } else if (lg == 1) {   // k 8..15 : xc[1..6], ea[0], ea[1]
            av0 = xc[1]; av1 = xc[2]; av2 = xc[3]; av3 = xc[4];
            av4 = xc[5]; av5 = xc[6]; av6 = ep[0]; av7 = ep[1];
        } else if (lg == 2) {   // k 16 : ea[2]; rest pad
            av0 = ep[2];
        }                        // lg == 3 : all pad

        short8v A;
        A[0] = (short)f2bf(av0); A[1] = (short)f2bf(av1);
        A[2] = (short)f2bf(av2); A[3] = (short)f2bf(av3);
        A[4] = (short)f2bf(av4); A[5] = (short)f2bf(av5);
        A[6] = (short)f2bf(av6); A[7] = (short)f2bf(av7);

        float4v Z = {0.f, 0.f, 0.f, 0.f};
        float4v C[8];
        #pragma unroll
        for (int t = 0; t < 8; ++t)
            C[t] = __builtin_amdgcn_mfma_f32_16x16x32_bf16(A, B1[t], Z, 0, 0, 0);

        // relu + bias + GEMM2 partials.
        // C layout (m89): col = l15 = hidden (within tile t), row = lg*4+reg = edge.
        float p00 = 0.f, p01 = 0.f, p02 = 0.f;
        float p10 = 0.f, p11 = 0.f, p12 = 0.f;
        float p20 = 0.f, p21 = 0.f, p22 = 0.f;
        float p30 = 0.f, p31 = 0.f, p32 = 0.f;
        #pragma unroll
        for (int t = 0; t < 8; ++t) {
            float h0 = fmaxf(C[t][0] + b1v[t], 0.f);
            float h1 = fmaxf(C[t][1] + b1v[t], 0.f);
            float h2 = fmaxf(C[t][2] + b1v[t], 0.f);
            float h3 = fmaxf(C[t][3] + b1v[t], 0.f);
            p00 += h0 * w2a[t]; p01 += h0 * w2b[t]; p02 += h0 * w2c[t];
            p10 += h1 * w2a[t]; p11 += h1 * w2b[t]; p12 += h1 * w2c[t];
            p20 += h2 * w2a[t]; p21 += h2 * w2b[t]; p22 += h2 * w2c[t];
            p30 += h3 * w2a[t]; p31 += h3 * w2b[t]; p32 += h3 * w2c[t];
        }
        // butterfly over the 16 hidden-lanes (same lane-group)
        #pragma unroll
        for (int m = 1; m < 16; m <<= 1) {
            p00 += __shfl_xor(p00, m, 16); p01 += __shfl_xor(p01, m, 16); p02 += __shfl_xor(p02, m, 16);
            p10 += __shfl_xor(p10, m, 16); p11 += __shfl_xor(p11, m, 16); p12 += __shfl_xor(p12, m, 16);
            p20 += __shfl_xor(p20, m, 16); p21 += __shfl_xor(p21, m, 16); p22 += __shfl_xor(p22, m, 16);
            p30 += __shfl_xor(p30, m, 16); p31 += __shfl_xor(p31, m, 16); p32 += __shfl_xor(p32, m, 16);
        }
        if (l15 < 4) {
            float o0 = (l15 == 0) ? p00 : (l15 == 1) ? p10 : (l15 == 2) ? p20 : p30;
            float o1 = (l15 == 0) ? p01 : (l15 == 1) ? p11 : (l15 == 2) ? p21 : p31;
            float o2 = (l15 == 0) ? p02 : (l15 == 1) ? p12 : (l15 == 2) ? p22 : p32;
            size_t off = (size_t)(tile * 16 + lg * 4 + l15) * 3;
            eab[off + 0] = o0 + bb0;
            eab[off + 1] = o1 + bb1;
            eab[off + 2] = o2 + bb2;
        }
    }
}

// ---------------- segment reduce: 16 lanes per node ----------------
__global__ __launch_bounds__(256) void reduce_kernel(
    const float* __restrict__ eab, const unsigned* __restrict__ start,
    const float* __restrict__ u, const int* __restrict__ batch,
    float* __restrict__ nred)
{
    int gid = blockIdx.x * 256 + threadIdx.x;
    int n = gid >> 4, sub = gid & 15;
    if (n >= NN) return;
    unsigned sbeg = start[n], send = start[n + 1];

    float s0 = 0.f, s1 = 0.f, s2 = 0.f;
    float m0 = -__builtin_inff(), m1 = -__builtin_inff(), m2 = -__builtin_inff();
    for (unsigned k = sbeg + sub; k < send; k += 16) {
        float v0 = eab[(size_t)k * 3 + 0];
        float v1 = eab[(size_t)k * 3 + 1];
        float v2 = eab[(size_t)k * 3 + 2];
        s0 += v0; s1 += v1; s2 += v2;
        m0 = fmaxf(m0, v0); m1 = fmaxf(m1, v1); m2 = fmaxf(m2, v2);
    }
    #pragma unroll
    for (int msk = 1; msk < 16; msk <<= 1) {
        s0 += __shfl_xor(s0, msk, 16);
        s1 += __shfl_xor(s1, msk, 16);
        s2 += __shfl_xor(s2, msk, 16);
        m0 = fmaxf(m0, __shfl_xor(m0, msk, 16));
        m1 = fmaxf(m1, __shfl_xor(m1, msk, 16));
        m2 = fmaxf(m2, __shfl_xor(m2, msk, 16));
    }
    if (sub == 0) {
        float deg = (float)(send - sbeg);
        if (send == sbeg) { m0 = 0.f; m1 = 0.f; m2 = 0.f; }
        float inv = 1.f / fmaxf(deg, 1.f);
        int b = batch[n];
        float* o = nred + (size_t)n * 12;
        o[0] = s0; o[1] = s1; o[2] = s2;
        o[3] = m0; o[4] = m1; o[5] = m2;
        o[6] = s0 * inv; o[7] = s1 * inv; o[8] = s2 * inv;
        o[9] = u[b * 2 + 0]; o[10] = u[b * 2 + 1];
    }
}

// ---------------- node MLP: wave-per-node, weight-stationary ----------------
#define NMLP_BLOCKS 1024
#define NMLP_WAVES (NMLP_BLOCKS * 4)
__global__ __launch_bounds__(256, 4) void nodemlp_kernel(
    const float* x_in, const float* __restrict__ nred,
    const float* __restrict__ wt, const float* __restrict__ b2,
    float* x_out)
{
    int lane = threadIdx.x & 63;
    int wid = (blockIdx.x * 256 + threadIdx.x) >> 6;

    const float* ra = wt + lane * 28;
    const float* rb = wt + (lane + 64) * 28;
    float a0 = ra[0], a1 = ra[1], a2 = ra[2], a3 = ra[3], a4 = ra[4], a5 = ra[5],
          a6 = ra[6], a7 = ra[7], a8 = ra[8], a9 = ra[9], a10 = ra[10], a11 = ra[11],
          a12 = ra[12], a13 = ra[13], a14 = ra[14], a15 = ra[15], a16 = ra[16], a17 = ra[17],
          ab = ra[18], p0 = ra[19], p1 = ra[20], p2 = ra[21], p3 = ra[22], p4 = ra[23],
          p5 = ra[24], p6 = ra[25];
    float b0 = rb[0], b1 = rb[1], b2_ = rb[2], b3 = rb[3], b4 = rb[4], b5 = rb[5],
          b6 = rb[6], b7 = rb[7], b8 = rb[8], b9 = rb[9], b10 = rb[10], b11 = rb[11],
          b12 = rb[12], b13 = rb[13], b14 = rb[14], b15 = rb[15], b16 = rb[16], b17 = rb[17],
          bb = rb[18], q0 = rb[19], q1 = rb[20], q2 = rb[21], q3 = rb[22], q4 = rb[23],
          q5 = rb[24], q6 = rb[25];

    asm volatile("" : "+v"(a0), "+v"(a1), "+v"(a2), "+v"(a3), "+v"(a4), "+v"(a5),
                      "+v"(a6), "+v"(a7), "+v"(a8), "+v"(a9), "+v"(a10), "+v"(a11),
                      "+v"(a12), "+v"(a13), "+v"(a14), "+v"(a15), "+v"(a16), "+v"(a17),
                      "+v"(ab), "+v"(p0), "+v"(p1), "+v"(p2), "+v"(p3), "+v"(p4),
                      "+v"(p5), "+v"(p6));
    asm volatile("" : "+v"(b0), "+v"(b1), "+v"(b2_), "+v"(b3), "+v"(b4), "+v"(b5),
                      "+v"(b6), "+v"(b7), "+v"(b8), "+v"(b9), "+v"(b10), "+v"(b11),
                      "+v"(b12), "+v"(b13), "+v"(b14), "+v"(b15), "+v"(b16), "+v"(b17),
                      "+v"(bb), "+v"(q0), "+v"(q1), "+v"(q2), "+v"(q3), "+v"(q4),
                      "+v"(q5), "+v"(q6));

    float B0 = b2[0], B1 = b2[1], B2 = b2[2], B3 = b2[3], B4 = b2[4], B5 = b2[5], B6 = b2[6];

    const int nper = (NN + NMLP_WAVES - 1) / NMLP_WAVES;   // 25
    int n0 = wid * nper;
    int n1 = n0 + nper; if (n1 > NN) n1 = NN;

    #pragma unroll 2
    for (int n = n0; n < n1; ++n) {
        int nu = __builtin_amdgcn_readfirstlane(n);
        const float* xp = x_in + (size_t)nu * 7;
        const float* rp = nred + (size_t)nu * 12;
        float i0 = xp[0], i1 = xp[1], i2 = xp[2], i3 = xp[3], i4 = xp[4], i5 = xp[5], i6 = xp[6];
        float s0 = rp[0], s1 = rp[1], s2 = rp[2];
        float m0 = rp[3], m1 = rp[4], m2 = rp[5];
        float e0 = rp[6], e1 = rp[7], e2 = rp[8];
        float u0 = rp[9], u1 = rp[10];

        float ha = ab, hb = bb;
        ha += i0 * a0;  hb += i0 * b0;
        ha += i1 * a1;  hb += i1 * b1;
        ha += i2 * a2;  hb += i2 * b2_;
        ha += i3 * a3;  hb += i3 * b3;
        ha += i4 * a4;  hb += i4 * b4;
        ha += i5 * a5;  hb += i5 * b5;
        ha += i6 * a6;  hb += i6 * b6;
        ha += s0 * a7;  hb += s0 * b7;
        ha += s1 * a8;  hb += s1 * b8;
        ha += s2 * a9;  hb += s2 * b9;
        ha += m0 * a10; hb += m0 * b10;
        ha += m1 * a11; hb += m1 * b11;
        ha += m2 * a12; hb += m2 * b12;
        ha += e0 * a13; hb += e0 * b13;
        ha += e1 * a14; hb += e1 * b14;
        ha += e2 * a15; hb += e2 * b15;
        ha += u0 * a16; hb += u0 * b16;
        ha += u1 * a17; hb += u1 * b17;
        ha = fmaxf(ha, 0.f); hb = fmaxf(hb, 0.f);

        float c0 = ha * p0 + hb * q0;
        float c1 = ha * p1 + hb * q1;
        float c2 = ha * p2 + hb * q2;
        float c3 = ha * p3 + hb * q3;
        float c4 = ha * p4 + hb * q4;
        float c5 = ha * p5 + hb * q5;
        float c6 = ha * p6 + hb * q6;
        #pragma unroll
        for (int msk = 1; msk < 64; msk <<= 1) {
            c0 += __shfl_xor(c0, msk);
            c1 += __shfl_xor(c1, msk);
            c2 += __shfl_xor(c2, msk);
            c3 += __shfl_xor(c3, msk);
            c4 += __shfl_xor(c4, msk);
            c5 += __shfl_xor(c5, msk);
            c6 += __shfl_xor(c6, msk);
        }
        float o = c0 + B0;
        if (lane == 1) o = c1 + B1;
        if (lane == 2) o = c2 + B2;
        if (lane == 3) o = c3 + B3;
        if (lane == 4) o = c4 + B4;
        if (lane == 5) o = c5 + B5;
        if (lane == 6) o = c6 + B6;
        if (lane < 7) x_out[(size_t)nu * 7 + lane] = o;
    }
}

// ---------------- fused graph pool + output head (block per graph) ----------
__global__ __launch_bounds__(256) void pool_head_kernel(
    const float* __restrict__ x, const int* __restrict__ gstart,
    const float* __restrict__ u,
    const float* __restrict__ oW1, const float* __restrict__ ob1,
    const float* __restrict__ oW2, const float* __restrict__ ob2,
    const float* __restrict__ oW3, const float* __restrict__ ob3,
    const float* __restrict__ oW4, const float* __restrict__ ob4,
    float* __restrict__ out)
{
    int g = blockIdx.x, tid = threadIdx.x;
    int lane = tid & 63, wv = tid >> 6;
    int gs = gstart[g], ge = gstart[g + 1];

    float s0 = 0.f, s1 = 0.f, s2 = 0.f, s3 = 0.f, s4 = 0.f, s5 = 0.f, s6 = 0.f;
    float m0 = -__builtin_inff(), m1 = m0, m2 = m0, m3 = m0, m4 = m0, m5 = m0, m6 = m0;
    for (int n = gs + tid; n < ge; n += 256) {
        const float* xp = x + (size_t)n * 7;
        float v0 = xp[0], v1 = xp[1], v2 = xp[2], v3 = xp[3], v4 = xp[4], v5 = xp[5], v6 = xp[6];
        s0 += v0; s1 += v1; s2 += v2; s3 += v3; s4 += v4; s5 += v5; s6 += v6;
        m0 = fmaxf(m0, v0); m1 = fmaxf(m1, v1); m2 = fmaxf(m2, v2); m3 = fmaxf(m3, v3);
        m4 = fmaxf(m4, v4); m5 = fmaxf(m5, v5); m6 = fmaxf(m6, v6);
    }
    #pragma unroll
    for (int msk = 1; msk < 64; msk <<= 1) {
        s0 += __shfl_xor(s0, msk); s1 += __shfl_xor(s1, msk); s2 += __shfl_xor(s2, msk);
        s3 += __shfl_xor(s3, msk); s4 += __shfl_xor(s4, msk); s5 += __shfl_xor(s5, msk);
        s6 += __shfl_xor(s6, msk);
        m0 = fmaxf(m0, __shfl_xor(m0, msk)); m1 = fmaxf(m1, __shfl_xor(m1, msk));
        m2 = fmaxf(m2, __shfl_xor(m2, msk)); m3 = fmaxf(m3, __shfl_xor(m3, msk));
        m4 = fmaxf(m4, __shfl_xor(m4, msk)); m5 = fmaxf(m5, __shfl_xor(m5, msk));
        m6 = fmaxf(m6, __shfl_xor(m6, msk));
    }
    __shared__ float red[4][14];
    __shared__ float hin[23];
    __shared__ float ha[128];
    __shared__ float hbuf[128];
    if (lane == 0) {
        red[wv][0] = s0; red[wv][1] = s1; red[wv][2] = s2; red[wv][3] = s3;
        red[wv][4] = s4; red[wv][5] = s5; red[wv][6] = s6;
        red[wv][7] = m0; red[wv][8] = m1; red[wv][9] = m2; red[wv][10] = m3;
        red[wv][11] = m4; red[wv][12] = m5; red[wv][13] = m6;
    }
    __syncthreads();
    if (tid < 7) {
        float S = red[0][tid] + red[1][tid] + red[2][tid] + red[3][tid];
        float M = fmaxf(fmaxf(red[0][7 + tid], red[1][7 + tid]),
                        fmaxf(red[2][7 + tid], red[3][7 + tid]));
        float cntf = (float)(ge - gs);
        if (ge == gs) M = 0.f;
        hin[tid] = S;
        hin[7 + tid] = S / fmaxf(cntf, 1.f);
        hin[14 + tid] = M;
    }
    if (tid < 2) hin[21 + tid] = u[g * 2 + tid];
    __syncthreads();

    float h = 0.f;
    if (tid < 128) {
        h = ob1[tid];
        for (int i = 0; i < 23; ++i) h += hin[i] * oW1[i * 128 + tid];
        ha[tid] = fmaxf(h, 0.f);
    }
    __syncthreads();
    if (tid < 128) {
        h = ob2[tid];
        for (int i = 0; i < 128; ++i) h += ha[i] * oW2[i * 128 + tid];
        hbuf[tid] = fmaxf(h, 0.f);
    }
    __syncthreads();
    if (tid < 128) {
        h = ob3[tid];
        for (int i = 0; i < 128; ++i) h += hbuf[i] * oW3[i * 128 + tid];
        ha[tid] = fmaxf(h, 0.f) * oW4[tid];
    }
    __syncthreads();
    if (tid == 0) {
        float acc = ob4[0];
        for (int i = 0; i < 128; ++i) acc += ha[i];
        out[g] = acc;
    }
}

extern "C" void kernel_launch(void* const* d_in, const int* in_sizes, int n_in,
                              void* d_out, int out_size, void* d_ws, size_t ws_size,
                              hipStream_t stream) {
    const float* x         = (const float*)d_in[0];
    const float* edge_attr = (const float*)d_in[1];
    const float* u         = (const float*)d_in[2];
    const float* eW1 = (const float*)d_in[3];
    const float* eb1 = (const float*)d_in[4];
    const float* eW2 = (const float*)d_in[5];
    const float* eb2 = (const float*)d_in[6];
    const float* nW1 = (const float*)d_in[7];
    const float* nb1 = (const float*)d_in[8];
    const float* nW2 = (const float*)d_in[9];
    const float* nb2 = (const float*)d_in[10];
    const float* oW1 = (const float*)d_in[11];
    const float* ob1 = (const float*)d_in[12];
    const float* oW2 = (const float*)d_in[13];
    const float* ob2 = (const float*)d_in[14];
    const float* oW3 = (const float*)d_in[15];
    const float* ob3 = (const float*)d_in[16];
    const float* oW4 = (const float*)d_in[17];
    const float* ob4 = (const float*)d_in[18];
    const int* edge_index = (const int*)d_in[19];
    const int* batch      = (const int*)d_in[20];
    const int* row = edge_index;
    const int* col = edge_index + NE;

    // workspace layout
    float* ws        = (float*)d_ws;
    float* eab       = ws;                                  // E*3
    float* ws_x      = eab + (size_t)NE * 3;                // N*7
    int2*  rc        = (int2*)(ws_x + (size_t)NN * 7);      // E
    float* nred      = (float*)(rc + (size_t)NE);           // N*12
    unsigned* rank   = (unsigned*)(nred + (size_t)NN * 12); // E
    unsigned* cnt    = rank + (size_t)NE;                   // N
    unsigned* startv = cnt + NN;                            // N+1
    unsigned* bsum   = startv + NN + 1;                     // 512
    unsigned* boff   = bsum + 512;                          // 512
    int* gstart      = (int*)(boff + 512);                  // 257 (+pad)
    float* nwt       = (float*)(gstart + 260);              // 2*128*28
    float* w2f       = nwt + 2 * 128 * 28;                  // 2*1536
    float* b1f       = w2f + 2 * 1536;                      // 2*512
    uintptr_t ewb    = ((uintptr_t)(b1f + 2 * 512) + 15) & ~(uintptr_t)15;
    short* ewf       = (short*)ewb;                         // 2*4096 shorts

    dim3 b256(256);
    dim3 ge_(NE / 256);                 // 6250, exact
    dim3 gn(NB);                        // 391

    // zero cnt
    zero_kernel<<<(NN + 255) / 256, b256, 0, stream>>>((float*)cnt, NN);

    // CSR + graph ranges: one atomic pass (rank) -> scan -> atomic-free scatter
    rank_kernel<<<ge_, b256, 0, stream>>>(col, cnt, rank);
    gbound_kernel<<<gn, b256, 0, stream>>>(batch, gstart);
    bsum_kernel<<<gn, b256, 0, stream>>>(cnt, bsum);
    bscan_kernel<<<1, 512, 0, stream>>>(bsum, boff);
    start_kernel<<<gn, b256, 0, stream>>>(cnt, boff, startv);
    scatter_kernel<<<ge_, b256, 0, stream>>>(row, col, edge_attr, startv, rank, rc, eab);

    // weight prep (edge MFMA tables + node rows)
    {
        int t = 2 * 4096 + 2 * 1536 + 2 * 512 + 2 * 128 * 28;  // 19456
        prep_kernel<<<(t + 255) / 256, b256, 0, stream>>>(
            eW1, eb1, eW2, nW1, nb1, nW2, ewf, w2f, b1f, nwt);
    }

    dim3 gr((NN * 16 + 255) / 256);   // 6250 blocks for reduce
    dim3 gemf(2048);                  // edge MFMA grid (8192 waves, grid-stride)

    // ---- layer 0 ----
    edge_kernel<<<gemf, b256, 0, stream>>>(x, eab, rc, ewf, w2f, b1f, eb2);
    reduce_kernel<<<gr, b256, 0, stream>>>(eab, startv, u, batch, nred);
    nodemlp_kernel<<<NMLP_BLOCKS, b256, 0, stream>>>(x, nred, nwt, nb2, ws_x);

    // ---- layer 1 ----
    edge_kernel<<<gemf, b256, 0, stream>>>(ws_x, eab, rc,
        ewf + 4096, w2f + 1536, b1f + 512, eb2 + 3);
    reduce_kernel<<<gr, b256, 0, stream>>>(eab, startv, u, batch, nred);
    nodemlp_kernel<<<NMLP_BLOCKS, b256, 0, stream>>>(ws_x, nred, nwt + 128 * 28, nb2 + 7, ws_x);

    // ---- fused pool + head ----
    pool_head_kernel<<<NG, b256, 0, stream>>>(ws_x, gstart, u,
        oW1, ob1, oW2, ob2, oW3, ob3, oW4, ob4, (float*)d_out);
}